// Round 7
// baseline (746.781 us; speedup 1.0000x reference)
//
#include <hip/hip_runtime.h>

#define NN 50000
#define NE 800000

// ---------------- wave helpers ----------------
__device__ __forceinline__ float wsum64(float v) {
#pragma unroll
  for (int off = 32; off; off >>= 1) v += __shfl_xor(v, off, 64);
  return v;
}
__device__ __forceinline__ float lrelu(float x) { return x > 0.0f ? x : 0.2f * x; }
#define RFL(v) __builtin_amdgcn_readfirstlane(v)

// ---------------- CSR build ----------------
__global__ void zero_int_k(int* __restrict__ p, int n) {
  int i = blockIdx.x * 256 + threadIdx.x;
  if (i < n) p[i] = 0;
}

__global__ void count_deg_k(const int* __restrict__ dst, int* __restrict__ deg) {
  int e = blockIdx.x * 256 + threadIdx.x;
  if (e < NE) atomicAdd(&deg[dst[e]], 1);
}

__global__ __launch_bounds__(1024) void scan_k(const int* __restrict__ deg,
                                               int* __restrict__ row_ptr,
                                               int* __restrict__ cursor) {
  __shared__ int woff[16];
  int tid = threadIdx.x;
  int lane = tid & 63, wv = tid >> 6;
  const int CH = (NN + 1023) / 1024;  // 49
  int lo = tid * CH;
  int hi = lo + CH;
  if (lo > NN) lo = NN;
  if (hi > NN) hi = NN;
  int s = 0;
  for (int i = lo; i < hi; ++i) s += deg[i];
  int incl = s;
#pragma unroll
  for (int off = 1; off < 64; off <<= 1) {
    int t = __shfl_up(incl, off, 64);
    if (lane >= off) incl += t;
  }
  if (lane == 63) woff[wv] = incl;
  __syncthreads();
  if (tid == 0) {
    int run = 0;
#pragma unroll
    for (int w = 0; w < 16; ++w) { int t = woff[w]; woff[w] = run; run += t; }
    row_ptr[NN] = run;  // == NE
  }
  __syncthreads();
  int run = incl - s + woff[wv];
  for (int i = lo; i < hi; ++i) {
    row_ptr[i] = run;
    cursor[i] = run;
    run += deg[i];
  }
}

__global__ void fill_csr_k(const int* __restrict__ src, const int* __restrict__ dst,
                           int* __restrict__ cursor, int* __restrict__ csr_src) {
  int e = blockIdx.x * 256 + threadIdx.x;
  if (e < NE) {
    int pos = atomicAdd(&cursor[dst[e]], 1);
    csr_src[pos] = src[e];
  }
}

// ---------------- tiny precomputes ----------------
__global__ void compute_q_k(const float* __restrict__ W, const float* __restrict__ al,
                            const float* __restrict__ ar, float* __restrict__ Q, int KDIM) {
  int idx = blockIdx.x * 256 + threadIdx.x;
  if (idx >= KDIM * 8) return;
  int k = idx >> 3, c = idx & 7;
  int h = c & 3;
  const float* av = (c < 4 ? al : ar) + h * 64;
  const float* wrow = W + (size_t)k * 256 + h * 64;
  float s = 0.0f;
  for (int m = 0; m < 64; ++m) s += wrow[m] * av[m];
  Q[idx] = s;
}

__global__ void compute_m_k(const float* __restrict__ Wh2, const float* __restrict__ Wo,
                            float* __restrict__ M) {
  int row = blockIdx.x;  // 0..255
  int d = threadIdx.x;   // 0..63
  int h = row >> 6, k = row & 63;
  float s = 0.0f;
  for (int j = 0; j < 64; ++j)
    s += Wh2[k * 256 + h * 64 + j] * Wo[(h * 64 + j) * 64 + d];
  M[row * 64 + d] = s;
}

__global__ void compute_c_k(const float* __restrict__ bh2, const float* __restrict__ Wo,
                            const float* __restrict__ bo, float* __restrict__ cvec) {
  int d = threadIdx.x;
  if (d >= 64) return;
  float s = bo[d];
  for (int m = 0; m < 256; ++m) s += bh2[m] * Wo[m * 64 + d];
  cvec[d] = s;
}

// ---------------- el/er for layer 1 ----------------
__global__ __launch_bounds__(256) void eler_l1_k(const float* __restrict__ X,
                                                 const float* __restrict__ Q,
                                                 float* __restrict__ elp,
                                                 float* __restrict__ erp) {
  int n = RFL(blockIdx.x * 4 + (threadIdx.x >> 6));
  int lane = threadIdx.x & 63;
  float2 xv = *(const float2*)&X[(n << 7) + (lane << 1)];
  float4 qa0 = *(const float4*)&Q[(lane * 2) * 8];
  float4 qb0 = *(const float4*)&Q[(lane * 2) * 8 + 4];
  float4 qa1 = *(const float4*)&Q[(lane * 2 + 1) * 8];
  float4 qb1 = *(const float4*)&Q[(lane * 2 + 1) * 8 + 4];
  float p[8];
  p[0] = xv.x * qa0.x + xv.y * qa1.x; p[1] = xv.x * qa0.y + xv.y * qa1.y;
  p[2] = xv.x * qa0.z + xv.y * qa1.z; p[3] = xv.x * qa0.w + xv.y * qa1.w;
  p[4] = xv.x * qb0.x + xv.y * qb1.x; p[5] = xv.x * qb0.y + xv.y * qb1.y;
  p[6] = xv.x * qb0.z + xv.y * qb1.z; p[7] = xv.x * qb0.w + xv.y * qb1.w;
#pragma unroll
  for (int c = 0; c < 8; ++c) p[c] = wsum64(p[c]);
  if (lane == 0) {
    *(float4*)&elp[n << 2] = make_float4(p[0], p[1], p[2], p[3]);
    *(float4*)&erp[n << 2] = make_float4(p[4], p[5], p[6], p[7]);
  }
}

// weight vector from gathered el4 + node er4, masked
__device__ __forceinline__ float4 wexp4(const float4& l4, const float4& er4, bool on) {
  float4 w = make_float4(0.f, 0.f, 0.f, 0.f);
  if (on) {
    w.x = __expf(lrelu(l4.x + er4.x));
    w.y = __expf(lrelu(l4.y + er4.y));
    w.z = __expf(lrelu(l4.z + er4.z));
    w.w = __expf(lrelu(l4.w + er4.w));
  }
  return w;
}

// ---------------- fused hidden layer (prefetch + f4 GEMV) ----------------
__global__ __launch_bounds__(256, 7) void fused_hidden_k(
    const float* __restrict__ x, const float* __restrict__ el,
    const float* __restrict__ er, const float* __restrict__ W,
    const float* __restrict__ b, const float* __restrict__ Qn,
    const int* __restrict__ row_ptr, const int* __restrict__ csr_src,
    float* __restrict__ hout, float* __restrict__ eln, float* __restrict__ ern) {
  __shared__ float gs[4][1024];
  __shared__ int s_lds[4][64];
  __shared__ float4 w_lds[4][64];
  int wave = threadIdx.x >> 6, lane = threadIdx.x & 63;
  int base = (blockIdx.x * 4 + wave) * 4;
  float* gw = gs[wave];
  int* s_l = s_lds[wave];
  float4* w_l = w_lds[wave];
  // prologue prefetch for t=0
  int beg = row_ptr[base];
  int end = row_ptr[base + 1];
  int sv_p = csr_src[min(beg + lane, NE - 1)];
  float4 l4_p = *(const float4*)&el[sv_p << 2];
#pragma unroll 1
  for (int t = 0; t < 4; ++t) {
    int n = base + t;
    float4 er4 = *(const float4*)&er[n << 2];
    int cnt = min(64, end - beg);
    float4 wv = wexp4(l4_p, er4, lane < cnt);
    s_l[lane] = sv_p;
    w_l[lane] = wv;
    float p0 = wv.x, p1 = wv.y, p2 = wv.z, p3 = wv.w;
    int begE = beg + 64, endE = end;  // extra-chunk range
    // prefetch t+1 (beg(t+1) == end(t))
    if (t < 3) {
      int begN = end;
      end = row_ptr[n + 2];
      beg = begN;
      sv_p = csr_src[min(begN + lane, NE - 1)];
      l4_p = *(const float4*)&el[sv_p << 2];
    }
    float a0 = 0.f, a1 = 0.f, a2 = 0.f, a3 = 0.f;
#define FMA4(Q, X)            \
  do {                        \
    float4 qq = (Q);          \
    a0 = fmaf(qq.x, (X), a0); \
    a1 = fmaf(qq.y, (X), a1); \
    a2 = fmaf(qq.z, (X), a2); \
    a3 = fmaf(qq.w, (X), a3); \
  } while (0)
    {
      int j = 0;
      for (; j + 8 <= cnt; j += 8) {
        int t0 = RFL(s_l[j + 0]), t1 = RFL(s_l[j + 1]);
        int t2 = RFL(s_l[j + 2]), t3 = RFL(s_l[j + 3]);
        int t4 = RFL(s_l[j + 4]), t5 = RFL(s_l[j + 5]);
        int t6 = RFL(s_l[j + 6]), t7 = RFL(s_l[j + 7]);
        float x0 = x[(t0 << 6) + lane], x1 = x[(t1 << 6) + lane];
        float x2 = x[(t2 << 6) + lane], x3 = x[(t3 << 6) + lane];
        float x4 = x[(t4 << 6) + lane], x5 = x[(t5 << 6) + lane];
        float x6 = x[(t6 << 6) + lane], x7 = x[(t7 << 6) + lane];
        FMA4(w_l[j + 0], x0); FMA4(w_l[j + 1], x1);
        FMA4(w_l[j + 2], x2); FMA4(w_l[j + 3], x3);
        FMA4(w_l[j + 4], x4); FMA4(w_l[j + 5], x5);
        FMA4(w_l[j + 6], x6); FMA4(w_l[j + 7], x7);
      }
      for (; j < cnt; ++j) {
        int t0 = RFL(s_l[j]);
        float x0 = x[(t0 << 6) + lane];
        FMA4(w_l[j], x0);
      }
    }
    // extra chunks (deg > 64), inline phase-1
    for (int j0 = begE; j0 < endE; j0 += 64) {
      int c2 = min(64, endE - j0);
      int sv2 = csr_src[min(j0 + lane, NE - 1)];
      float4 l42 = *(const float4*)&el[sv2 << 2];
      float4 wv2 = wexp4(l42, er4, lane < c2);
      s_l[lane] = sv2;
      w_l[lane] = wv2;
      p0 += wv2.x; p1 += wv2.y; p2 += wv2.z; p3 += wv2.w;
      int j = 0;
      for (; j + 8 <= c2; j += 8) {
        int t0 = RFL(s_l[j + 0]), t1 = RFL(s_l[j + 1]);
        int t2 = RFL(s_l[j + 2]), t3 = RFL(s_l[j + 3]);
        int t4 = RFL(s_l[j + 4]), t5 = RFL(s_l[j + 5]);
        int t6 = RFL(s_l[j + 6]), t7 = RFL(s_l[j + 7]);
        float x0 = x[(t0 << 6) + lane], x1 = x[(t1 << 6) + lane];
        float x2 = x[(t2 << 6) + lane], x3 = x[(t3 << 6) + lane];
        float x4 = x[(t4 << 6) + lane], x5 = x[(t5 << 6) + lane];
        float x6 = x[(t6 << 6) + lane], x7 = x[(t7 << 6) + lane];
        FMA4(w_l[j + 0], x0); FMA4(w_l[j + 1], x1);
        FMA4(w_l[j + 2], x2); FMA4(w_l[j + 3], x3);
        FMA4(w_l[j + 4], x4); FMA4(w_l[j + 5], x5);
        FMA4(w_l[j + 6], x6); FMA4(w_l[j + 7], x7);
      }
      for (; j < c2; ++j) {
        int t0 = RFL(s_l[j]);
        float x0 = x[(t0 << 6) + lane];
        FMA4(w_l[j], x0);
      }
    }
#undef FMA4
    float sw0 = wsum64(p0), sw1 = wsum64(p1), sw2 = wsum64(p2), sw3 = wsum64(p3);
    float i0 = sw0 > 0.f ? 1.0f / sw0 : 0.f;
    float i1 = sw1 > 0.f ? 1.0f / sw1 : 0.f;
    float i2 = sw2 > 0.f ? 1.0f / sw2 : 0.f;
    float i3 = sw3 > 0.f ? 1.0f / sw3 : 0.f;
    gw[t * 256 + 0 * 64 + lane] = a0 * i0;
    gw[t * 256 + 1 * 64 + lane] = a1 * i1;
    gw[t * 256 + 2 * 64 + lane] = a2 * i2;
    gw[t * 256 + 3 * 64 + lane] = a3 * i3;
  }
  // f4 GEMV: y[t][lane] = sum_{row=h*64+k} g[t][row]*W[k*256+h*64+lane]
  float y0 = 0.f, y1 = 0.f, y2 = 0.f, y3 = 0.f;
  for (int rr = 0; rr < 256; rr += 4) {
    int h = rr >> 6, k = rr & 63;
    const float* wp = &W[k * 256 + (h << 6) + lane];
    float w0 = wp[0], w1 = wp[256], w2 = wp[512], w3 = wp[768];
    float4 g0 = *(const float4*)&gw[0 * 256 + rr];
    float4 g1 = *(const float4*)&gw[1 * 256 + rr];
    float4 g2 = *(const float4*)&gw[2 * 256 + rr];
    float4 g3 = *(const float4*)&gw[3 * 256 + rr];
    y0 = fmaf(g0.x, w0, y0); y0 = fmaf(g0.y, w1, y0);
    y0 = fmaf(g0.z, w2, y0); y0 = fmaf(g0.w, w3, y0);
    y1 = fmaf(g1.x, w0, y1); y1 = fmaf(g1.y, w1, y1);
    y1 = fmaf(g1.z, w2, y1); y1 = fmaf(g1.w, w3, y1);
    y2 = fmaf(g2.x, w0, y2); y2 = fmaf(g2.y, w1, y2);
    y2 = fmaf(g2.z, w2, y2); y2 = fmaf(g2.w, w3, y2);
    y3 = fmaf(g3.x, w0, y3); y3 = fmaf(g3.y, w1, y3);
    y3 = fmaf(g3.z, w2, y3); y3 = fmaf(g3.w, w3, y3);
  }
  float bsum = b[lane] + b[64 + lane] + b[128 + lane] + b[192 + lane];
  float4 qa = *(const float4*)&Qn[lane * 8];
  float4 qb = *(const float4*)&Qn[lane * 8 + 4];
  float ys[4] = {y0, y1, y2, y3};
#pragma unroll
  for (int t = 0; t < 4; ++t) {
    int n = base + t;
    float yv = 0.25f * (ys[t] + bsum);
    hout[(n << 6) + lane] = yv;
    float e0 = wsum64(yv * qa.x), e1 = wsum64(yv * qa.y);
    float e2 = wsum64(yv * qa.z), e3 = wsum64(yv * qa.w);
    float r0 = wsum64(yv * qb.x), r1 = wsum64(yv * qb.y);
    float r2 = wsum64(yv * qb.z), r3 = wsum64(yv * qb.w);
    if (lane == 0) {
      *(float4*)&eln[n << 2] = make_float4(e0, e1, e2, e3);
      *(float4*)&ern[n << 2] = make_float4(r0, r1, r2, r3);
    }
  }
}

// ---------------- fused layer 1 (dim128; prefetch + 2-node-group f4 GEMV) ------
__global__ __launch_bounds__(256, 7) void fused_l1_k(
    const float* __restrict__ x, const float* __restrict__ el,
    const float* __restrict__ er, const float* __restrict__ W,
    const float* __restrict__ b, const float* __restrict__ Qn,
    const int* __restrict__ row_ptr, const int* __restrict__ csr_src,
    float* __restrict__ hout, float* __restrict__ eln, float* __restrict__ ern) {
  __shared__ float gs[4][1024];  // 2 nodes x 512
  __shared__ int s_lds[4][64];
  __shared__ float4 w_lds[4][64];
  int wave = threadIdx.x >> 6, lane = threadIdx.x & 63;
  int base = (blockIdx.x * 4 + wave) * 4;
  float* gw = gs[wave];
  int* s_l = s_lds[wave];
  float4* w_l = w_lds[wave];
  int lane2 = lane << 1;
  float ys[4];
  int beg = row_ptr[base];
  int end = row_ptr[base + 1];
  int sv_p = csr_src[min(beg + lane, NE - 1)];
  float4 l4_p = *(const float4*)&el[sv_p << 2];
#pragma unroll 1
  for (int t = 0; t < 4; ++t) {
    int n = base + t;
    int g01 = t & 1;
    float4 er4 = *(const float4*)&er[n << 2];
    int cnt = min(64, end - beg);
    float4 wv = wexp4(l4_p, er4, lane < cnt);
    s_l[lane] = sv_p;
    w_l[lane] = wv;
    float p0 = wv.x, p1 = wv.y, p2 = wv.z, p3 = wv.w;
    int begE = beg + 64, endE = end;
    if (t < 3) {
      int begN = end;
      end = row_ptr[n + 2];
      beg = begN;
      sv_p = csr_src[min(begN + lane, NE - 1)];
      l4_p = *(const float4*)&el[sv_p << 2];
    }
    float a0x = 0.f, a0y = 0.f, a1x = 0.f, a1y = 0.f;
    float a2x = 0.f, a2y = 0.f, a3x = 0.f, a3y = 0.f;
#define FMA8(Q, X)                \
  do {                            \
    float4 qq = (Q);              \
    a0x = fmaf(qq.x, (X).x, a0x); \
    a0y = fmaf(qq.x, (X).y, a0y); \
    a1x = fmaf(qq.y, (X).x, a1x); \
    a1y = fmaf(qq.y, (X).y, a1y); \
    a2x = fmaf(qq.z, (X).x, a2x); \
    a2y = fmaf(qq.z, (X).y, a2y); \
    a3x = fmaf(qq.w, (X).x, a3x); \
    a3y = fmaf(qq.w, (X).y, a3y); \
  } while (0)
    {
      int j = 0;
      for (; j + 4 <= cnt; j += 4) {
        int t0 = RFL(s_l[j + 0]), t1 = RFL(s_l[j + 1]);
        int t2 = RFL(s_l[j + 2]), t3 = RFL(s_l[j + 3]);
        float2 x0 = *(const float2*)&x[(t0 << 7) + lane2];
        float2 x1 = *(const float2*)&x[(t1 << 7) + lane2];
        float2 x2 = *(const float2*)&x[(t2 << 7) + lane2];
        float2 x3 = *(const float2*)&x[(t3 << 7) + lane2];
        FMA8(w_l[j + 0], x0); FMA8(w_l[j + 1], x1);
        FMA8(w_l[j + 2], x2); FMA8(w_l[j + 3], x3);
      }
      for (; j < cnt; ++j) {
        int t0 = RFL(s_l[j]);
        float2 x0 = *(const float2*)&x[(t0 << 7) + lane2];
        FMA8(w_l[j], x0);
      }
    }
    for (int j0 = begE; j0 < endE; j0 += 64) {
      int c2 = min(64, endE - j0);
      int sv2 = csr_src[min(j0 + lane, NE - 1)];
      float4 l42 = *(const float4*)&el[sv2 << 2];
      float4 wv2 = wexp4(l42, er4, lane < c2);
      s_l[lane] = sv2;
      w_l[lane] = wv2;
      p0 += wv2.x; p1 += wv2.y; p2 += wv2.z; p3 += wv2.w;
      int j = 0;
      for (; j + 4 <= c2; j += 4) {
        int t0 = RFL(s_l[j + 0]), t1 = RFL(s_l[j + 1]);
        int t2 = RFL(s_l[j + 2]), t3 = RFL(s_l[j + 3]);
        float2 x0 = *(const float2*)&x[(t0 << 7) + lane2];
        float2 x1 = *(const float2*)&x[(t1 << 7) + lane2];
        float2 x2 = *(const float2*)&x[(t2 << 7) + lane2];
        float2 x3 = *(const float2*)&x[(t3 << 7) + lane2];
        FMA8(w_l[j + 0], x0); FMA8(w_l[j + 1], x1);
        FMA8(w_l[j + 2], x2); FMA8(w_l[j + 3], x3);
      }
      for (; j < c2; ++j) {
        int t0 = RFL(s_l[j]);
        float2 x0 = *(const float2*)&x[(t0 << 7) + lane2];
        FMA8(w_l[j], x0);
      }
    }
#undef FMA8
    float sw0 = wsum64(p0), sw1 = wsum64(p1), sw2 = wsum64(p2), sw3 = wsum64(p3);
    float i0 = sw0 > 0.f ? 1.0f / sw0 : 0.f;
    float i1 = sw1 > 0.f ? 1.0f / sw1 : 0.f;
    float i2 = sw2 > 0.f ? 1.0f / sw2 : 0.f;
    float i3 = sw3 > 0.f ? 1.0f / sw3 : 0.f;
    *(float2*)&gw[g01 * 512 + 0 * 128 + lane2] = make_float2(a0x * i0, a0y * i0);
    *(float2*)&gw[g01 * 512 + 1 * 128 + lane2] = make_float2(a1x * i1, a1y * i1);
    *(float2*)&gw[g01 * 512 + 2 * 128 + lane2] = make_float2(a2x * i2, a2y * i2);
    *(float2*)&gw[g01 * 512 + 3 * 128 + lane2] = make_float2(a3x * i3, a3y * i3);
    if (g01 == 1) {
      // GEMV for this 2-node group: row = h*128+k, W[k*256 + h*64 + lane]
      float yA = 0.f, yB = 0.f;
      for (int rr = 0; rr < 512; rr += 4) {
        int h = rr >> 7, k = rr & 127;
        const float* wp = &W[k * 256 + (h << 6) + lane];
        float w0 = wp[0], w1 = wp[256], w2 = wp[512], w3 = wp[768];
        float4 gA = *(const float4*)&gw[0 * 512 + rr];
        float4 gB = *(const float4*)&gw[1 * 512 + rr];
        yA = fmaf(gA.x, w0, yA); yA = fmaf(gA.y, w1, yA);
        yA = fmaf(gA.z, w2, yA); yA = fmaf(gA.w, w3, yA);
        yB = fmaf(gB.x, w0, yB); yB = fmaf(gB.y, w1, yB);
        yB = fmaf(gB.z, w2, yB); yB = fmaf(gB.w, w3, yB);
      }
      ys[t - 1] = yA;
      ys[t] = yB;
    }
  }
  float bsum = b[lane] + b[64 + lane] + b[128 + lane] + b[192 + lane];
  float4 qa = *(const float4*)&Qn[lane * 8];
  float4 qb = *(const float4*)&Qn[lane * 8 + 4];
#pragma unroll
  for (int t = 0; t < 4; ++t) {
    int n = base + t;
    float yv = 0.25f * (ys[t] + bsum);
    hout[(n << 6) + lane] = yv;
    float e0 = wsum64(yv * qa.x), e1 = wsum64(yv * qa.y);
    float e2 = wsum64(yv * qa.z), e3 = wsum64(yv * qa.w);
    float r0 = wsum64(yv * qb.x), r1 = wsum64(yv * qb.y);
    float r2 = wsum64(yv * qb.z), r3 = wsum64(yv * qb.w);
    if (lane == 0) {
      *(float4*)&eln[n << 2] = make_float4(e0, e1, e2, e3);
      *(float4*)&ern[n << 2] = make_float4(r0, r1, r2, r3);
    }
  }
}

// ---------------- fused final (prefetch + f4 GEMV(M) + LayerNorm) --------------
__global__ __launch_bounds__(256, 7) void fused_final_k(
    const float* __restrict__ x, const float* __restrict__ el,
    const float* __restrict__ er, const float* __restrict__ M,
    const float* __restrict__ cvec, const int* __restrict__ row_ptr,
    const int* __restrict__ csr_src, float* __restrict__ out) {
  __shared__ float gs[4][1024];
  __shared__ int s_lds[4][64];
  __shared__ float4 w_lds[4][64];
  int wave = threadIdx.x >> 6, lane = threadIdx.x & 63;
  int base = (blockIdx.x * 4 + wave) * 4;
  float* gw = gs[wave];
  int* s_l = s_lds[wave];
  float4* w_l = w_lds[wave];
  int beg = row_ptr[base];
  int end = row_ptr[base + 1];
  int sv_p = csr_src[min(beg + lane, NE - 1)];
  float4 l4_p = *(const float4*)&el[sv_p << 2];
#pragma unroll 1
  for (int t = 0; t < 4; ++t) {
    int n = base + t;
    float4 er4 = *(const float4*)&er[n << 2];
    int cnt = min(64, end - beg);
    float4 wv = wexp4(l4_p, er4, lane < cnt);
    s_l[lane] = sv_p;
    w_l[lane] = wv;
    float p0 = wv.x, p1 = wv.y, p2 = wv.z, p3 = wv.w;
    int begE = beg + 64, endE = end;
    if (t < 3) {
      int begN = end;
      end = row_ptr[n + 2];
      beg = begN;
      sv_p = csr_src[min(begN + lane, NE - 1)];
      l4_p = *(const float4*)&el[sv_p << 2];
    }
    float a0 = 0.f, a1 = 0.f, a2 = 0.f, a3 = 0.f;
#define FMA4(Q, X)            \
  do {                        \
    float4 qq = (Q);          \
    a0 = fmaf(qq.x, (X), a0); \
    a1 = fmaf(qq.y, (X), a1); \
    a2 = fmaf(qq.z, (X), a2); \
    a3 = fmaf(qq.w, (X), a3); \
  } while (0)
    {
      int j = 0;
      for (; j + 8 <= cnt; j += 8) {
        int t0 = RFL(s_l[j + 0]), t1 = RFL(s_l[j + 1]);
        int t2 = RFL(s_l[j + 2]), t3 = RFL(s_l[j + 3]);
        int t4 = RFL(s_l[j + 4]), t5 = RFL(s_l[j + 5]);
        int t6 = RFL(s_l[j + 6]), t7 = RFL(s_l[j + 7]);
        float x0 = x[(t0 << 6) + lane], x1 = x[(t1 << 6) + lane];
        float x2 = x[(t2 << 6) + lane], x3 = x[(t3 << 6) + lane];
        float x4 = x[(t4 << 6) + lane], x5 = x[(t5 << 6) + lane];
        float x6 = x[(t6 << 6) + lane], x7 = x[(t7 << 6) + lane];
        FMA4(w_l[j + 0], x0); FMA4(w_l[j + 1], x1);
        FMA4(w_l[j + 2], x2); FMA4(w_l[j + 3], x3);
        FMA4(w_l[j + 4], x4); FMA4(w_l[j + 5], x5);
        FMA4(w_l[j + 6], x6); FMA4(w_l[j + 7], x7);
      }
      for (; j < cnt; ++j) {
        int t0 = RFL(s_l[j]);
        float x0 = x[(t0 << 6) + lane];
        FMA4(w_l[j], x0);
      }
    }
    for (int j0 = begE; j0 < endE; j0 += 64) {
      int c2 = min(64, endE - j0);
      int sv2 = csr_src[min(j0 + lane, NE - 1)];
      float4 l42 = *(const float4*)&el[sv2 << 2];
      float4 wv2 = wexp4(l42, er4, lane < c2);
      s_l[lane] = sv2;
      w_l[lane] = wv2;
      p0 += wv2.x; p1 += wv2.y; p2 += wv2.z; p3 += wv2.w;
      int j = 0;
      for (; j + 8 <= c2; j += 8) {
        int t0 = RFL(s_l[j + 0]), t1 = RFL(s_l[j + 1]);
        int t2 = RFL(s_l[j + 2]), t3 = RFL(s_l[j + 3]);
        int t4 = RFL(s_l[j + 4]), t5 = RFL(s_l[j + 5]);
        int t6 = RFL(s_l[j + 6]), t7 = RFL(s_l[j + 7]);
        float x0 = x[(t0 << 6) + lane], x1 = x[(t1 << 6) + lane];
        float x2 = x[(t2 << 6) + lane], x3 = x[(t3 << 6) + lane];
        float x4 = x[(t4 << 6) + lane], x5 = x[(t5 << 6) + lane];
        float x6 = x[(t6 << 6) + lane], x7 = x[(t7 << 6) + lane];
        FMA4(w_l[j + 0], x0); FMA4(w_l[j + 1], x1);
        FMA4(w_l[j + 2], x2); FMA4(w_l[j + 3], x3);
        FMA4(w_l[j + 4], x4); FMA4(w_l[j + 5], x5);
        FMA4(w_l[j + 6], x6); FMA4(w_l[j + 7], x7);
      }
      for (; j < c2; ++j) {
        int t0 = RFL(s_l[j]);
        float x0 = x[(t0 << 6) + lane];
        FMA4(w_l[j], x0);
      }
    }
#undef FMA4
    float sw0 = wsum64(p0), sw1 = wsum64(p1), sw2 = wsum64(p2), sw3 = wsum64(p3);
    float i0 = sw0 > 0.f ? 1.0f / sw0 : 0.f;
    float i1 = sw1 > 0.f ? 1.0f / sw1 : 0.f;
    float i2 = sw2 > 0.f ? 1.0f / sw2 : 0.f;
    float i3 = sw3 > 0.f ? 1.0f / sw3 : 0.f;
    gw[t * 256 + 0 * 64 + lane] = a0 * i0;
    gw[t * 256 + 1 * 64 + lane] = a1 * i1;
    gw[t * 256 + 2 * 64 + lane] = a2 * i2;
    gw[t * 256 + 3 * 64 + lane] = a3 * i3;
  }
  float y0 = 0.f, y1 = 0.f, y2 = 0.f, y3 = 0.f;
  for (int rr = 0; rr < 256; rr += 4) {
    const float* wp = &M[(rr << 6) + lane];
    float w0 = wp[0], w1 = wp[64], w2 = wp[128], w3 = wp[192];
    float4 g0 = *(const float4*)&gw[0 * 256 + rr];
    float4 g1 = *(const float4*)&gw[1 * 256 + rr];
    float4 g2 = *(const float4*)&gw[2 * 256 + rr];
    float4 g3 = *(const float4*)&gw[3 * 256 + rr];
    y0 = fmaf(g0.x, w0, y0); y0 = fmaf(g0.y, w1, y0);
    y0 = fmaf(g0.z, w2, y0); y0 = fmaf(g0.w, w3, y0);
    y1 = fmaf(g1.x, w0, y1); y1 = fmaf(g1.y, w1, y1);
    y1 = fmaf(g1.z, w2, y1); y1 = fmaf(g1.w, w3, y1);
    y2 = fmaf(g2.x, w0, y2); y2 = fmaf(g2.y, w1, y2);
    y2 = fmaf(g2.z, w2, y2); y2 = fmaf(g2.w, w3, y2);
    y3 = fmaf(g3.x, w0, y3); y3 = fmaf(g3.y, w1, y3);
    y3 = fmaf(g3.z, w2, y3); y3 = fmaf(g3.w, w3, y3);
  }
  float cl = cvec[lane];
  float ys[4] = {y0 + cl, y1 + cl, y2 + cl, y3 + cl};
#pragma unroll
  for (int t = 0; t < 4; ++t) {
    int n = base + t;
    float y = ys[t];
    float mu = wsum64(y) * (1.0f / 64.0f);
    float dv = y - mu;
    float var = wsum64(dv * dv) * (1.0f / 64.0f);
    out[(n << 6) + lane] = dv * rsqrtf(var + 1e-5f);
  }
}

// ---------------- launch ----------------
extern "C" void kernel_launch(void* const* d_in, const int* in_sizes, int n_in,
                              void* d_out, int out_size, void* d_ws, size_t ws_size,
                              hipStream_t stream) {
  const float* in_feat = (const float*)d_in[0];
  const int* src = (const int*)d_in[1];
  const int* dst = (const int*)d_in[2];
  const float* W1 = (const float*)d_in[3];
  const float* al1 = (const float*)d_in[4];
  const float* ar1 = (const float*)d_in[5];
  const float* b1 = (const float*)d_in[6];
  const float* Wh = (const float*)d_in[7];   // [3][64][256]
  const float* alh = (const float*)d_in[8];  // [3][4][64]
  const float* arh = (const float*)d_in[9];  // [3][4][64]
  const float* bh = (const float*)d_in[10];  // [3][256]
  const float* Wo = (const float*)d_in[11];  // [256][64]
  const float* bo = (const float*)d_in[12];  // [64]
  float* out = (float*)d_out;

  char* ws = (char*)d_ws;
  size_t off = 0;
  auto alloc = [&](size_t bytes) {
    void* p = ws + off;
    off = (off + bytes + 255) & ~(size_t)255;
    return p;
  };
  float* h_a = (float*)alloc((size_t)NN * 64 * 4);
  float* h_b = (float*)alloc((size_t)NN * 64 * 4);
  float* el_a = (float*)alloc((size_t)NN * 4 * 4);
  float* er_a = (float*)alloc((size_t)NN * 4 * 4);
  float* el_b = (float*)alloc((size_t)NN * 4 * 4);
  float* er_b = (float*)alloc((size_t)NN * 4 * 4);
  float* Q1 = (float*)alloc(128 * 8 * 4);
  float* Q2 = (float*)alloc(64 * 8 * 4);
  float* Q3 = (float*)alloc(64 * 8 * 4);
  float* Q4 = (float*)alloc(64 * 8 * 4);
  float* M = (float*)alloc(256 * 64 * 4);
  float* cvec = (float*)alloc(64 * 4);
  int* deg = (int*)alloc((size_t)NN * 4);
  int* row_ptr = (int*)alloc((size_t)(NN + 1) * 4);
  int* cursor = (int*)alloc((size_t)NN * 4);
  int* csr_src = (int*)alloc((size_t)NE * 4);
  (void)ws_size; (void)in_sizes; (void)n_in; (void)out_size;

  // CSR build
  zero_int_k<<<(NN + 255) / 256, 256, 0, stream>>>(deg, NN);
  count_deg_k<<<(NE + 255) / 256, 256, 0, stream>>>(dst, deg);
  scan_k<<<1, 1024, 0, stream>>>(deg, row_ptr, cursor);
  fill_csr_k<<<(NE + 255) / 256, 256, 0, stream>>>(src, dst, cursor, csr_src);

  // tiny precomputes
  compute_q_k<<<4, 256, 0, stream>>>(W1, al1, ar1, Q1, 128);
  compute_q_k<<<2, 256, 0, stream>>>(Wh + 0 * 64 * 256, alh + 0 * 256, arh + 0 * 256, Q2, 64);
  compute_q_k<<<2, 256, 0, stream>>>(Wh + 1 * 64 * 256, alh + 1 * 256, arh + 1 * 256, Q3, 64);
  compute_q_k<<<2, 256, 0, stream>>>(Wh + 2 * 64 * 256, alh + 2 * 256, arh + 2 * 256, Q4, 64);
  compute_m_k<<<256, 64, 0, stream>>>(Wh + 2 * 64 * 256, Wo, M);
  compute_c_k<<<1, 64, 0, stream>>>(bh + 2 * 256, Wo, bo, cvec);

  const int FUSED_GRID = NN / 16;  // 3125
  const int ELER_GRID = NN / 4;    // 12500

  // layer 1
  eler_l1_k<<<ELER_GRID, 256, 0, stream>>>(in_feat, Q1, el_a, er_a);
  fused_l1_k<<<FUSED_GRID, 256, 0, stream>>>(in_feat, el_a, er_a, W1, b1, Q2,
                                             row_ptr, csr_src, h_a, el_b, er_b);
  // hidden layers
  fused_hidden_k<<<FUSED_GRID, 256, 0, stream>>>(h_a, el_b, er_b, Wh + 0 * 64 * 256,
                                                 bh + 0 * 256, Q3, row_ptr, csr_src,
                                                 h_b, el_a, er_a);
  fused_hidden_k<<<FUSED_GRID, 256, 0, stream>>>(h_b, el_a, er_a, Wh + 1 * 64 * 256,
                                                 bh + 1 * 256, Q4, row_ptr, csr_src,
                                                 h_a, el_b, er_b);
  // final layer + out_ln + LayerNorm
  fused_final_k<<<FUSED_GRID, 256, 0, stream>>>(h_a, el_b, er_b, M, cvec,
                                                row_ptr, csr_src, out);
}

// Round 8
// 696.012 us; speedup vs baseline: 1.0729x; 1.0729x over previous
//
#include <hip/hip_runtime.h>

#define NN 50000
#define NE 800000

// ---------------- wave helpers ----------------
__device__ __forceinline__ float wsum64(float v) {
#pragma unroll
  for (int off = 32; off; off >>= 1) v += __shfl_xor(v, off, 64);
  return v;
}
__device__ __forceinline__ float lrelu(float x) { return x > 0.0f ? x : 0.2f * x; }
#define RFL(v) __builtin_amdgcn_readfirstlane(v)

// ---------------- CSR build ----------------
__global__ void zero_int_k(int* __restrict__ p, int n) {
  int i = blockIdx.x * 256 + threadIdx.x;
  if (i < n) p[i] = 0;
}

__global__ void count_deg_k(const int* __restrict__ dst, int* __restrict__ deg) {
  int e = blockIdx.x * 256 + threadIdx.x;
  if (e < NE) atomicAdd(&deg[dst[e]], 1);
}

__global__ __launch_bounds__(1024) void scan_k(const int* __restrict__ deg,
                                               int* __restrict__ row_ptr,
                                               int* __restrict__ cursor) {
  __shared__ int woff[16];
  int tid = threadIdx.x;
  int lane = tid & 63, wv = tid >> 6;
  const int CH = (NN + 1023) / 1024;  // 49
  int lo = tid * CH;
  int hi = lo + CH;
  if (lo > NN) lo = NN;
  if (hi > NN) hi = NN;
  int s = 0;
  for (int i = lo; i < hi; ++i) s += deg[i];
  int incl = s;
#pragma unroll
  for (int off = 1; off < 64; off <<= 1) {
    int t = __shfl_up(incl, off, 64);
    if (lane >= off) incl += t;
  }
  if (lane == 63) woff[wv] = incl;
  __syncthreads();
  if (tid == 0) {
    int run = 0;
#pragma unroll
    for (int w = 0; w < 16; ++w) { int t = woff[w]; woff[w] = run; run += t; }
    row_ptr[NN] = run;  // == NE
  }
  __syncthreads();
  int run = incl - s + woff[wv];
  for (int i = lo; i < hi; ++i) {
    row_ptr[i] = run;
    cursor[i] = run;
    run += deg[i];
  }
}

__global__ void fill_csr_k(const int* __restrict__ src, const int* __restrict__ dst,
                           int* __restrict__ cursor, int* __restrict__ csr_src) {
  int e = blockIdx.x * 256 + threadIdx.x;
  if (e < NE) {
    int pos = atomicAdd(&cursor[dst[e]], 1);
    csr_src[pos] = src[e];
  }
}

// ---------------- tiny precomputes ----------------
__global__ void compute_q_k(const float* __restrict__ W, const float* __restrict__ al,
                            const float* __restrict__ ar, float* __restrict__ Q, int KDIM) {
  int idx = blockIdx.x * 256 + threadIdx.x;
  if (idx >= KDIM * 8) return;
  int k = idx >> 3, c = idx & 7;
  int h = c & 3;
  const float* av = (c < 4 ? al : ar) + h * 64;
  const float* wrow = W + (size_t)k * 256 + h * 64;
  float s = 0.0f;
  for (int m = 0; m < 64; ++m) s += wrow[m] * av[m];
  Q[idx] = s;
}

__global__ void compute_m_k(const float* __restrict__ Wh2, const float* __restrict__ Wo,
                            float* __restrict__ M) {
  int row = blockIdx.x;  // 0..255
  int d = threadIdx.x;   // 0..63
  int h = row >> 6, k = row & 63;
  float s = 0.0f;
  for (int j = 0; j < 64; ++j)
    s += Wh2[k * 256 + h * 64 + j] * Wo[(h * 64 + j) * 64 + d];
  M[row * 64 + d] = s;
}

__global__ void compute_c_k(const float* __restrict__ bh2, const float* __restrict__ Wo,
                            const float* __restrict__ bo, float* __restrict__ cvec) {
  int d = threadIdx.x;
  if (d >= 64) return;
  float s = bo[d];
  for (int m = 0; m < 256; ++m) s += bh2[m] * Wo[m * 64 + d];
  cvec[d] = s;
}

// ---------------- el/er for layer 1 ----------------
__global__ __launch_bounds__(256) void eler_l1_k(const float* __restrict__ X,
                                                 const float* __restrict__ Q,
                                                 float* __restrict__ elp,
                                                 float* __restrict__ erp) {
  int n = RFL(blockIdx.x * 4 + (threadIdx.x >> 6));
  int lane = threadIdx.x & 63;
  float2 xv = *(const float2*)&X[(n << 7) + (lane << 1)];
  float4 qa0 = *(const float4*)&Q[(lane * 2) * 8];
  float4 qb0 = *(const float4*)&Q[(lane * 2) * 8 + 4];
  float4 qa1 = *(const float4*)&Q[(lane * 2 + 1) * 8];
  float4 qb1 = *(const float4*)&Q[(lane * 2 + 1) * 8 + 4];
  float p[8];
  p[0] = xv.x * qa0.x + xv.y * qa1.x; p[1] = xv.x * qa0.y + xv.y * qa1.y;
  p[2] = xv.x * qa0.z + xv.y * qa1.z; p[3] = xv.x * qa0.w + xv.y * qa1.w;
  p[4] = xv.x * qb0.x + xv.y * qb1.x; p[5] = xv.x * qb0.y + xv.y * qb1.y;
  p[6] = xv.x * qb0.z + xv.y * qb1.z; p[7] = xv.x * qb0.w + xv.y * qb1.w;
#pragma unroll
  for (int c = 0; c < 8; ++c) p[c] = wsum64(p[c]);
  if (lane == 0) {
    *(float4*)&elp[n << 2] = make_float4(p[0], p[1], p[2], p[3]);
    *(float4*)&erp[n << 2] = make_float4(p[4], p[5], p[6], p[7]);
  }
}

// ---------------- fused hidden layer (R5 agg + f4 GEMV) ----------------
// Full wave per edge; lane (q=lane>>4, r=lane&15) owns head q, dims 4r..4r+3.
__global__ __launch_bounds__(256) void fused_hidden_k(
    const float* __restrict__ x, const float* __restrict__ el,
    const float* __restrict__ er, const float* __restrict__ W,
    const float* __restrict__ b, const float* __restrict__ Qn,
    const int* __restrict__ row_ptr, const int* __restrict__ csr_src,
    float* __restrict__ hout, float* __restrict__ eln, float* __restrict__ ern) {
  __shared__ float gs[4][1024];
  int wave = threadIdx.x >> 6, lane = threadIdx.x & 63;
  int q = lane >> 4, r = lane & 15;
  int base = (blockIdx.x * 4 + wave) * 4;
  float* gw = gs[wave];
  int r4 = r << 2;
#pragma unroll 1
  for (int t = 0; t < 4; ++t) {
    int n = RFL(base + t);
    int beg = row_ptr[n], end = row_ptr[n + 1];
    float erq = er[(n << 2) + q];
    float4 a = make_float4(0.f, 0.f, 0.f, 0.f);
    float sw = 0.f;
#define ESTEP(elv, xv)                      \
  do {                                      \
    float w = __expf(lrelu((elv) + erq));   \
    sw += w;                                \
    a.x = fmaf(w, (xv).x, a.x);             \
    a.y = fmaf(w, (xv).y, a.y);             \
    a.z = fmaf(w, (xv).z, a.z);             \
    a.w = fmaf(w, (xv).w, a.w);             \
  } while (0)
    int j = beg;
    for (; j + 8 <= end; j += 8) {
      int s0 = csr_src[j + 0], s1 = csr_src[j + 1];
      int s2 = csr_src[j + 2], s3 = csr_src[j + 3];
      int s4 = csr_src[j + 4], s5 = csr_src[j + 5];
      int s6 = csr_src[j + 6], s7 = csr_src[j + 7];
      float e0 = el[(s0 << 2) + q], e1 = el[(s1 << 2) + q];
      float e2 = el[(s2 << 2) + q], e3 = el[(s3 << 2) + q];
      float e4 = el[(s4 << 2) + q], e5 = el[(s5 << 2) + q];
      float e6 = el[(s6 << 2) + q], e7 = el[(s7 << 2) + q];
      float4 x0 = *(const float4*)&x[(s0 << 6) + r4];
      float4 x1 = *(const float4*)&x[(s1 << 6) + r4];
      float4 x2 = *(const float4*)&x[(s2 << 6) + r4];
      float4 x3 = *(const float4*)&x[(s3 << 6) + r4];
      float4 x4 = *(const float4*)&x[(s4 << 6) + r4];
      float4 x5 = *(const float4*)&x[(s5 << 6) + r4];
      float4 x6 = *(const float4*)&x[(s6 << 6) + r4];
      float4 x7 = *(const float4*)&x[(s7 << 6) + r4];
      ESTEP(e0, x0); ESTEP(e1, x1); ESTEP(e2, x2); ESTEP(e3, x3);
      ESTEP(e4, x4); ESTEP(e5, x5); ESTEP(e6, x6); ESTEP(e7, x7);
    }
    for (; j < end; ++j) {
      int s0 = csr_src[j];
      float e0 = el[(s0 << 2) + q];
      float4 x0 = *(const float4*)&x[(s0 << 6) + r4];
      ESTEP(e0, x0);
    }
#undef ESTEP
    float inv = sw > 0.f ? 1.0f / sw : 0.f;
    *(float4*)&gw[t * 256 + (q << 6) + r4] =
        make_float4(a.x * inv, a.y * inv, a.z * inv, a.w * inv);
  }
  // f4 GEMV: y[t][lane] = sum_{row=h*64+k} g[t][row] * W[k*256+h*64+lane]
  float y0 = 0.f, y1 = 0.f, y2 = 0.f, y3 = 0.f;
  for (int rr = 0; rr < 256; rr += 4) {
    int h = rr >> 6, k = rr & 63;
    const float* wp = &W[k * 256 + (h << 6) + lane];
    float w0 = wp[0], w1 = wp[256], w2 = wp[512], w3 = wp[768];
    float4 g0 = *(const float4*)&gw[0 * 256 + rr];
    float4 g1 = *(const float4*)&gw[1 * 256 + rr];
    float4 g2 = *(const float4*)&gw[2 * 256 + rr];
    float4 g3 = *(const float4*)&gw[3 * 256 + rr];
    y0 = fmaf(g0.x, w0, y0); y0 = fmaf(g0.y, w1, y0);
    y0 = fmaf(g0.z, w2, y0); y0 = fmaf(g0.w, w3, y0);
    y1 = fmaf(g1.x, w0, y1); y1 = fmaf(g1.y, w1, y1);
    y1 = fmaf(g1.z, w2, y1); y1 = fmaf(g1.w, w3, y1);
    y2 = fmaf(g2.x, w0, y2); y2 = fmaf(g2.y, w1, y2);
    y2 = fmaf(g2.z, w2, y2); y2 = fmaf(g2.w, w3, y2);
    y3 = fmaf(g3.x, w0, y3); y3 = fmaf(g3.y, w1, y3);
    y3 = fmaf(g3.z, w2, y3); y3 = fmaf(g3.w, w3, y3);
  }
  float bsum = b[lane] + b[64 + lane] + b[128 + lane] + b[192 + lane];
  float4 qa = *(const float4*)&Qn[lane * 8];
  float4 qb = *(const float4*)&Qn[lane * 8 + 4];
  float ys[4] = {y0, y1, y2, y3};
#pragma unroll
  for (int t = 0; t < 4; ++t) {
    int n = base + t;
    float yv = 0.25f * (ys[t] + bsum);
    hout[(n << 6) + lane] = yv;
    float e0 = wsum64(yv * qa.x), e1 = wsum64(yv * qa.y);
    float e2 = wsum64(yv * qa.z), e3 = wsum64(yv * qa.w);
    float r0 = wsum64(yv * qb.x), r1 = wsum64(yv * qb.y);
    float r2 = wsum64(yv * qb.z), r3 = wsum64(yv * qb.w);
    if (lane == 0) {
      *(float4*)&eln[n << 2] = make_float4(e0, e1, e2, e3);
      *(float4*)&ern[n << 2] = make_float4(r0, r1, r2, r3);
    }
  }
}

// ---------------- fused layer 1 (R5 agg + 2-node-group f4 GEMV) ----------------
// lane (q,r) owns head q, dims 8r..8r+7 (two float4s per edge).
__global__ __launch_bounds__(256) void fused_l1_k(
    const float* __restrict__ x, const float* __restrict__ el,
    const float* __restrict__ er, const float* __restrict__ W,
    const float* __restrict__ b, const float* __restrict__ Qn,
    const int* __restrict__ row_ptr, const int* __restrict__ csr_src,
    float* __restrict__ hout, float* __restrict__ eln, float* __restrict__ ern) {
  __shared__ float gs[4][1024];  // 2 nodes x 512
  int wave = threadIdx.x >> 6, lane = threadIdx.x & 63;
  int q = lane >> 4, r = lane & 15;
  int base = (blockIdx.x * 4 + wave) * 4;
  float* gw = gs[wave];
  int r8 = r << 3;
  float ys[4];
#pragma unroll 1
  for (int t = 0; t < 4; ++t) {
    int n = RFL(base + t);
    int g01 = t & 1;
    int beg = row_ptr[n], end = row_ptr[n + 1];
    float erq = er[(n << 2) + q];
    float4 aA = make_float4(0.f, 0.f, 0.f, 0.f);
    float4 aB = make_float4(0.f, 0.f, 0.f, 0.f);
    float sw = 0.f;
#define ESTEP(elv, xa, xb)                  \
  do {                                      \
    float w = __expf(lrelu((elv) + erq));   \
    sw += w;                                \
    aA.x = fmaf(w, (xa).x, aA.x);           \
    aA.y = fmaf(w, (xa).y, aA.y);           \
    aA.z = fmaf(w, (xa).z, aA.z);           \
    aA.w = fmaf(w, (xa).w, aA.w);           \
    aB.x = fmaf(w, (xb).x, aB.x);           \
    aB.y = fmaf(w, (xb).y, aB.y);           \
    aB.z = fmaf(w, (xb).z, aB.z);           \
    aB.w = fmaf(w, (xb).w, aB.w);           \
  } while (0)
    int j = beg;
    for (; j + 4 <= end; j += 4) {
      int s0 = csr_src[j + 0], s1 = csr_src[j + 1];
      int s2 = csr_src[j + 2], s3 = csr_src[j + 3];
      float e0 = el[(s0 << 2) + q], e1 = el[(s1 << 2) + q];
      float e2 = el[(s2 << 2) + q], e3 = el[(s3 << 2) + q];
      float4 xa0 = *(const float4*)&x[(s0 << 7) + r8];
      float4 xb0 = *(const float4*)&x[(s0 << 7) + r8 + 4];
      float4 xa1 = *(const float4*)&x[(s1 << 7) + r8];
      float4 xb1 = *(const float4*)&x[(s1 << 7) + r8 + 4];
      float4 xa2 = *(const float4*)&x[(s2 << 7) + r8];
      float4 xb2 = *(const float4*)&x[(s2 << 7) + r8 + 4];
      float4 xa3 = *(const float4*)&x[(s3 << 7) + r8];
      float4 xb3 = *(const float4*)&x[(s3 << 7) + r8 + 4];
      ESTEP(e0, xa0, xb0); ESTEP(e1, xa1, xb1);
      ESTEP(e2, xa2, xb2); ESTEP(e3, xa3, xb3);
    }
    for (; j < end; ++j) {
      int s0 = csr_src[j];
      float e0 = el[(s0 << 2) + q];
      float4 xa0 = *(const float4*)&x[(s0 << 7) + r8];
      float4 xb0 = *(const float4*)&x[(s0 << 7) + r8 + 4];
      ESTEP(e0, xa0, xb0);
    }
#undef ESTEP
    float inv = sw > 0.f ? 1.0f / sw : 0.f;
    *(float4*)&gw[g01 * 512 + (q << 7) + r8] =
        make_float4(aA.x * inv, aA.y * inv, aA.z * inv, aA.w * inv);
    *(float4*)&gw[g01 * 512 + (q << 7) + r8 + 4] =
        make_float4(aB.x * inv, aB.y * inv, aB.z * inv, aB.w * inv);
    if (g01 == 1) {
      // f4 GEMV for this 2-node group: row = h*128+k, W[k*256 + h*64 + lane]
      float yA = 0.f, yB = 0.f;
      for (int rr = 0; rr < 512; rr += 4) {
        int h = rr >> 7, k = rr & 127;
        const float* wp = &W[k * 256 + (h << 6) + lane];
        float w0 = wp[0], w1 = wp[256], w2 = wp[512], w3 = wp[768];
        float4 gA = *(const float4*)&gw[0 * 512 + rr];
        float4 gB = *(const float4*)&gw[1 * 512 + rr];
        yA = fmaf(gA.x, w0, yA); yA = fmaf(gA.y, w1, yA);
        yA = fmaf(gA.z, w2, yA); yA = fmaf(gA.w, w3, yA);
        yB = fmaf(gB.x, w0, yB); yB = fmaf(gB.y, w1, yB);
        yB = fmaf(gB.z, w2, yB); yB = fmaf(gB.w, w3, yB);
      }
      ys[t - 1] = yA;
      ys[t] = yB;
    }
  }
  float bsum = b[lane] + b[64 + lane] + b[128 + lane] + b[192 + lane];
  float4 qa = *(const float4*)&Qn[lane * 8];
  float4 qb = *(const float4*)&Qn[lane * 8 + 4];
#pragma unroll
  for (int t = 0; t < 4; ++t) {
    int n = base + t;
    float yv = 0.25f * (ys[t] + bsum);
    hout[(n << 6) + lane] = yv;
    float e0 = wsum64(yv * qa.x), e1 = wsum64(yv * qa.y);
    float e2 = wsum64(yv * qa.z), e3 = wsum64(yv * qa.w);
    float r0 = wsum64(yv * qb.x), r1 = wsum64(yv * qb.y);
    float r2 = wsum64(yv * qb.z), r3 = wsum64(yv * qb.w);
    if (lane == 0) {
      *(float4*)&eln[n << 2] = make_float4(e0, e1, e2, e3);
      *(float4*)&ern[n << 2] = make_float4(r0, r1, r2, r3);
    }
  }
}

// ---------------- fused final (R5 agg + f4 GEMV(M) + LayerNorm) ----------------
__global__ __launch_bounds__(256) void fused_final_k(
    const float* __restrict__ x, const float* __restrict__ el,
    const float* __restrict__ er, const float* __restrict__ M,
    const float* __restrict__ cvec, const int* __restrict__ row_ptr,
    const int* __restrict__ csr_src, float* __restrict__ out) {
  __shared__ float gs[4][1024];
  int wave = threadIdx.x >> 6, lane = threadIdx.x & 63;
  int q = lane >> 4, r = lane & 15;
  int base = (blockIdx.x * 4 + wave) * 4;
  float* gw = gs[wave];
  int r4 = r << 2;
#pragma unroll 1
  for (int t = 0; t < 4; ++t) {
    int n = RFL(base + t);
    int beg = row_ptr[n], end = row_ptr[n + 1];
    float erq = er[(n << 2) + q];
    float4 a = make_float4(0.f, 0.f, 0.f, 0.f);
    float sw = 0.f;
#define ESTEP(elv, xv)                      \
  do {                                      \
    float w = __expf(lrelu((elv) + erq));   \
    sw += w;                                \
    a.x = fmaf(w, (xv).x, a.x);             \
    a.y = fmaf(w, (xv).y, a.y);             \
    a.z = fmaf(w, (xv).z, a.z);             \
    a.w = fmaf(w, (xv).w, a.w);             \
  } while (0)
    int j = beg;
    for (; j + 8 <= end; j += 8) {
      int s0 = csr_src[j + 0], s1 = csr_src[j + 1];
      int s2 = csr_src[j + 2], s3 = csr_src[j + 3];
      int s4 = csr_src[j + 4], s5 = csr_src[j + 5];
      int s6 = csr_src[j + 6], s7 = csr_src[j + 7];
      float e0 = el[(s0 << 2) + q], e1 = el[(s1 << 2) + q];
      float e2 = el[(s2 << 2) + q], e3 = el[(s3 << 2) + q];
      float e4 = el[(s4 << 2) + q], e5 = el[(s5 << 2) + q];
      float e6 = el[(s6 << 2) + q], e7 = el[(s7 << 2) + q];
      float4 x0 = *(const float4*)&x[(s0 << 6) + r4];
      float4 x1 = *(const float4*)&x[(s1 << 6) + r4];
      float4 x2 = *(const float4*)&x[(s2 << 6) + r4];
      float4 x3 = *(const float4*)&x[(s3 << 6) + r4];
      float4 x4 = *(const float4*)&x[(s4 << 6) + r4];
      float4 x5 = *(const float4*)&x[(s5 << 6) + r4];
      float4 x6 = *(const float4*)&x[(s6 << 6) + r4];
      float4 x7 = *(const float4*)&x[(s7 << 6) + r4];
      ESTEP(e0, x0); ESTEP(e1, x1); ESTEP(e2, x2); ESTEP(e3, x3);
      ESTEP(e4, x4); ESTEP(e5, x5); ESTEP(e6, x6); ESTEP(e7, x7);
    }
    for (; j < end; ++j) {
      int s0 = csr_src[j];
      float e0 = el[(s0 << 2) + q];
      float4 x0 = *(const float4*)&x[(s0 << 6) + r4];
      ESTEP(e0, x0);
    }
#undef ESTEP
    float inv = sw > 0.f ? 1.0f / sw : 0.f;
    *(float4*)&gw[t * 256 + (q << 6) + r4] =
        make_float4(a.x * inv, a.y * inv, a.z * inv, a.w * inv);
  }
  float y0 = 0.f, y1 = 0.f, y2 = 0.f, y3 = 0.f;
  for (int rr = 0; rr < 256; rr += 4) {
    const float* wp = &M[(rr << 6) + lane];
    float w0 = wp[0], w1 = wp[64], w2 = wp[128], w3 = wp[192];
    float4 g0 = *(const float4*)&gw[0 * 256 + rr];
    float4 g1 = *(const float4*)&gw[1 * 256 + rr];
    float4 g2 = *(const float4*)&gw[2 * 256 + rr];
    float4 g3 = *(const float4*)&gw[3 * 256 + rr];
    y0 = fmaf(g0.x, w0, y0); y0 = fmaf(g0.y, w1, y0);
    y0 = fmaf(g0.z, w2, y0); y0 = fmaf(g0.w, w3, y0);
    y1 = fmaf(g1.x, w0, y1); y1 = fmaf(g1.y, w1, y1);
    y1 = fmaf(g1.z, w2, y1); y1 = fmaf(g1.w, w3, y1);
    y2 = fmaf(g2.x, w0, y2); y2 = fmaf(g2.y, w1, y2);
    y2 = fmaf(g2.z, w2, y2); y2 = fmaf(g2.w, w3, y2);
    y3 = fmaf(g3.x, w0, y3); y3 = fmaf(g3.y, w1, y3);
    y3 = fmaf(g3.z, w2, y3); y3 = fmaf(g3.w, w3, y3);
  }
  float cl = cvec[lane];
  float ys[4] = {y0 + cl, y1 + cl, y2 + cl, y3 + cl};
#pragma unroll
  for (int t = 0; t < 4; ++t) {
    int n = base + t;
    float y = ys[t];
    float mu = wsum64(y) * (1.0f / 64.0f);
    float dv = y - mu;
    float var = wsum64(dv * dv) * (1.0f / 64.0f);
    out[(n << 6) + lane] = dv * rsqrtf(var + 1e-5f);
  }
}

// ---------------- launch ----------------
extern "C" void kernel_launch(void* const* d_in, const int* in_sizes, int n_in,
                              void* d_out, int out_size, void* d_ws, size_t ws_size,
                              hipStream_t stream) {
  const float* in_feat = (const float*)d_in[0];
  const int* src = (const int*)d_in[1];
  const int* dst = (const int*)d_in[2];
  const float* W1 = (const float*)d_in[3];
  const float* al1 = (const float*)d_in[4];
  const float* ar1 = (const float*)d_in[5];
  const float* b1 = (const float*)d_in[6];
  const float* Wh = (const float*)d_in[7];   // [3][64][256]
  const float* alh = (const float*)d_in[8];  // [3][4][64]
  const float* arh = (const float*)d_in[9];  // [3][4][64]
  const float* bh = (const float*)d_in[10];  // [3][256]
  const float* Wo = (const float*)d_in[11];  // [256][64]
  const float* bo = (const float*)d_in[12];  // [64]
  float* out = (float*)d_out;

  char* ws = (char*)d_ws;
  size_t off = 0;
  auto alloc = [&](size_t bytes) {
    void* p = ws + off;
    off = (off + bytes + 255) & ~(size_t)255;
    return p;
  };
  float* h_a = (float*)alloc((size_t)NN * 64 * 4);
  float* h_b = (float*)alloc((size_t)NN * 64 * 4);
  float* el_a = (float*)alloc((size_t)NN * 4 * 4);
  float* er_a = (float*)alloc((size_t)NN * 4 * 4);
  float* el_b = (float*)alloc((size_t)NN * 4 * 4);
  float* er_b = (float*)alloc((size_t)NN * 4 * 4);
  float* Q1 = (float*)alloc(128 * 8 * 4);
  float* Q2 = (float*)alloc(64 * 8 * 4);
  float* Q3 = (float*)alloc(64 * 8 * 4);
  float* Q4 = (float*)alloc(64 * 8 * 4);
  float* M = (float*)alloc(256 * 64 * 4);
  float* cvec = (float*)alloc(64 * 4);
  int* deg = (int*)alloc((size_t)NN * 4);
  int* row_ptr = (int*)alloc((size_t)(NN + 1) * 4);
  int* cursor = (int*)alloc((size_t)NN * 4);
  int* csr_src = (int*)alloc((size_t)NE * 4);
  (void)ws_size; (void)in_sizes; (void)n_in; (void)out_size;

  // CSR build
  zero_int_k<<<(NN + 255) / 256, 256, 0, stream>>>(deg, NN);
  count_deg_k<<<(NE + 255) / 256, 256, 0, stream>>>(dst, deg);
  scan_k<<<1, 1024, 0, stream>>>(deg, row_ptr, cursor);
  fill_csr_k<<<(NE + 255) / 256, 256, 0, stream>>>(src, dst, cursor, csr_src);

  // tiny precomputes
  compute_q_k<<<4, 256, 0, stream>>>(W1, al1, ar1, Q1, 128);
  compute_q_k<<<2, 256, 0, stream>>>(Wh + 0 * 64 * 256, alh + 0 * 256, arh + 0 * 256, Q2, 64);
  compute_q_k<<<2, 256, 0, stream>>>(Wh + 1 * 64 * 256, alh + 1 * 256, arh + 1 * 256, Q3, 64);
  compute_q_k<<<2, 256, 0, stream>>>(Wh + 2 * 64 * 256, alh + 2 * 256, arh + 2 * 256, Q4, 64);
  compute_m_k<<<256, 64, 0, stream>>>(Wh + 2 * 64 * 256, Wo, M);
  compute_c_k<<<1, 64, 0, stream>>>(bh + 2 * 256, Wo, bo, cvec);

  const int FUSED_GRID = NN / 16;  // 3125
  const int ELER_GRID = NN / 4;    // 12500

  // layer 1
  eler_l1_k<<<ELER_GRID, 256, 0, stream>>>(in_feat, Q1, el_a, er_a);
  fused_l1_k<<<FUSED_GRID, 256, 0, stream>>>(in_feat, el_a, er_a, W1, b1, Q2,
                                             row_ptr, csr_src, h_a, el_b, er_b);
  // hidden layers
  fused_hidden_k<<<FUSED_GRID, 256, 0, stream>>>(h_a, el_b, er_b, Wh + 0 * 64 * 256,
                                                 bh + 0 * 256, Q3, row_ptr, csr_src,
                                                 h_b, el_a, er_a);
  fused_hidden_k<<<FUSED_GRID, 256, 0, stream>>>(h_b, el_a, er_a, Wh + 1 * 64 * 256,
                                                 bh + 1 * 256, Q4, row_ptr, csr_src,
                                                 h_a, el_b, er_b);
  // final layer + out_ln + LayerNorm
  fused_final_k<<<FUSED_GRID, 256, 0, stream>>>(h_a, el_b, er_b, M, cvec,
                                                row_ptr, csr_src, out);
}